// Round 1
// baseline (847.494 us; speedup 1.0000x reference)
//
#include <hip/hip_runtime.h>
#include <hip/hip_bf16.h>

#define N_NODES 8192

typedef __attribute__((ext_vector_type(8))) short short8;
typedef __attribute__((ext_vector_type(8))) unsigned short ushort8;
typedef __attribute__((ext_vector_type(4))) unsigned short ushort4v;
typedef __attribute__((ext_vector_type(4))) float floatx4;

__device__ inline unsigned short f2bf(float f) {
  unsigned int u = __float_as_uint(f);
  u = (u + 0x7FFFu + ((u >> 16) & 1u)) >> 16;  // RNE, no NaNs in this data
  return (unsigned short)u;
}

__device__ inline float waveSum(float s) {
#pragma unroll
  for (int off = 32; off >= 1; off >>= 1) s += __shfl_xor(s, off, 64);
  return s;
}

__device__ inline void acc4(float4& a, const float4 b) {
  a.x += b.x; a.y += b.y; a.z += b.z; a.w += b.w;
}
__device__ inline float hsum4(const float4 v) { return v.x + v.y + v.z + v.w; }

// ---------------------------------------------------------------------------
// K1: rowsums of adj_uu (y=0) and adj_cc (y=1), finalize dinv = rsqrt(1+sum)
// wave per row; 4 rows per block. grid (2048, 2) x 256
// ---------------------------------------------------------------------------
__global__ __launch_bounds__(256) void k_rowsum(const float* __restrict__ a_uu,
                                                const float* __restrict__ a_cc,
                                                float* __restrict__ dinv_uu,
                                                float* __restrict__ dinv_cc) {
  const float* A = (blockIdx.y == 0) ? a_uu : a_cc;
  float* dv = (blockIdx.y == 0) ? dinv_uu : dinv_cc;
  int w = threadIdx.x >> 6, l = threadIdx.x & 63;
  long row = (long)blockIdx.x * 4 + w;
  const float* rp = A + row * N_NODES + 4 * l;
  float s = 0.f;
#pragma unroll 2
  for (int i = 0; i < 32; i += 4) {
    float4 v0 = *(const float4*)(rp + 256 * (i + 0));
    float4 v1 = *(const float4*)(rp + 256 * (i + 1));
    float4 v2 = *(const float4*)(rp + 256 * (i + 2));
    float4 v3 = *(const float4*)(rp + 256 * (i + 3));
    s += hsum4(v0) + hsum4(v1) + hsum4(v2) + hsum4(v3);
  }
  s = waveSum(s);
  if (l == 0) dv[row] = rsqrtf(1.0f + s);
}

// ---------------------------------------------------------------------------
// K2: single pass over adj_uc producing row-sum partials and col-sum partials.
// Block covers 128 rows x 1024 cols; wave w handles 32 rows (full 1024 cols).
// rs_part[cc][row] (8 x 8192), cs_part[rc][col] (64 x 8192) - sole writers, no atomics.
// grid (64, 8) x 256
// ---------------------------------------------------------------------------
__global__ __launch_bounds__(256) void k_uc_partials(const float* __restrict__ adj,
                                                     float* __restrict__ rs_part,
                                                     float* __restrict__ cs_part) {
  __shared__ float cacc[4][1024];
  int t = threadIdx.x, w = t >> 6, l = t & 63;
  int rc = blockIdx.x, cc = blockIdx.y;
  int c0 = cc * 1024;
  int rbase = rc * 128 + w * 32;
  float4 ca0 = {0, 0, 0, 0}, ca1 = {0, 0, 0, 0}, ca2 = {0, 0, 0, 0}, ca3 = {0, 0, 0, 0};
  for (int kr = 0; kr < 32; kr += 2) {
    const float* p0 = adj + (long)(rbase + kr) * N_NODES + c0 + 4 * l;
    const float* p1 = p0 + N_NODES;
    float4 u0 = *(const float4*)(p0 + 0);
    float4 u1 = *(const float4*)(p0 + 256);
    float4 u2 = *(const float4*)(p0 + 512);
    float4 u3 = *(const float4*)(p0 + 768);
    float4 v0 = *(const float4*)(p1 + 0);
    float4 v1 = *(const float4*)(p1 + 256);
    float4 v2 = *(const float4*)(p1 + 512);
    float4 v3 = *(const float4*)(p1 + 768);
    acc4(ca0, u0); acc4(ca1, u1); acc4(ca2, u2); acc4(ca3, u3);
    acc4(ca0, v0); acc4(ca1, v1); acc4(ca2, v2); acc4(ca3, v3);
    float s0 = hsum4(u0) + hsum4(u1) + hsum4(u2) + hsum4(u3);
    float s1 = hsum4(v0) + hsum4(v1) + hsum4(v2) + hsum4(v3);
    s0 = waveSum(s0);
    s1 = waveSum(s1);
    if (l == 0) {
      rs_part[(long)cc * N_NODES + rbase + kr] = s0;
      rs_part[(long)cc * N_NODES + rbase + kr + 1] = s1;
    }
  }
  *(float4*)&cacc[w][0 + 4 * l] = ca0;
  *(float4*)&cacc[w][256 + 4 * l] = ca1;
  *(float4*)&cacc[w][512 + 4 * l] = ca2;
  *(float4*)&cacc[w][768 + 4 * l] = ca3;
  __syncthreads();
#pragma unroll
  for (int i = 0; i < 4; ++i) {
    int c = t + 256 * i;
    cs_part[(long)rc * N_NODES + c0 + c] = cacc[0][c] + cacc[1][c] + cacc[2][c] + cacc[3][c];
  }
}

// ---------------------------------------------------------------------------
// K3: reduce partials -> du = rsqrt(rowsum), dc = rsqrt(colsum). grid 32 x 256
// ---------------------------------------------------------------------------
__global__ __launch_bounds__(256) void k_finalize(const float* __restrict__ rs_part,
                                                  const float* __restrict__ cs_part,
                                                  float* __restrict__ du,
                                                  float* __restrict__ dc) {
  int i = blockIdx.x * 256 + threadIdx.x;
  float s = 0.f;
#pragma unroll
  for (int cc = 0; cc < 8; ++cc) s += rs_part[(long)cc * N_NODES + i];
  du[i] = rsqrtf(s);
  float c = 0.f;
#pragma unroll
  for (int rc = 0; rc < 64; ++rc) c += cs_part[(long)rc * N_NODES + i];
  dc[i] = rsqrtf(c);
}

// ---------------------------------------------------------------------------
// K0: P = proj_u @ weight_c (32x32). one block x 1024
// ---------------------------------------------------------------------------
__global__ void k_projw(const float* __restrict__ proj_u,
                        const float* __restrict__ weight_c, float* __restrict__ P) {
  int t = threadIdx.x;
  int i = t >> 5, j = t & 31;
  float s = 0.f;
#pragma unroll
  for (int k = 0; k < 32; ++k) s += proj_u[i * 32 + k] * weight_c[k * 32 + j];
  P[t] = s;
}

// ---------------------------------------------------------------------------
// K_sup: Bt[n][j] = bf16( dinv[j] * (X @ W)[j][n] ), transposed bf16 output
// y=0: X_U @ weight_s * dinv_uu ; y=1: X_C @ weight_s * dinv_cc ; y=2: X_U @ P * dc
// grid (1024, 3) x 256 (8 rows x 32 cols per block)
// ---------------------------------------------------------------------------
__global__ __launch_bounds__(256) void k_support(
    const float* __restrict__ X_U, const float* __restrict__ X_C,
    const float* __restrict__ weight_s, const float* __restrict__ P,
    const float* __restrict__ dinv_uu, const float* __restrict__ dinv_cc,
    const float* __restrict__ dc,
    unsigned short* __restrict__ bt_uu, unsigned short* __restrict__ bt_cc,
    unsigned short* __restrict__ bt_uc) {
  int m = blockIdx.y;
  const float* X = (m == 1) ? X_C : X_U;
  const float* W = (m == 2) ? P : weight_s;
  const float* dv = (m == 0) ? dinv_uu : (m == 1) ? dinv_cc : dc;
  unsigned short* bt = (m == 0) ? bt_uu : (m == 1) ? bt_cc : bt_uc;
  __shared__ float Wl[32][32];
  __shared__ float Xl[8][32];
  int t = threadIdx.x;
#pragma unroll
  for (int i = 0; i < 4; ++i) {
    int idx = t + 256 * i;
    Wl[idx >> 5][idx & 31] = W[idx];
  }
  int r = t >> 5, n = t & 31;
  int j0 = blockIdx.x * 8;
  Xl[r][n] = X[(long)(j0 + r) * 32 + n];
  __syncthreads();
  float s = 0.f;
#pragma unroll
  for (int k = 0; k < 32; ++k) s += Xl[r][k] * Wl[k][n];
  s *= dv[j0 + r];
  bt[(long)n * N_NODES + j0 + r] = f2bf(s);
}

// ---------------------------------------------------------------------------
// K5: out[i,n] = dsc[i] * sum_j adj[i,j]*Bt[n][j]   (M=K=8192, N=32)
// M_tile=32, BK=128, 256 threads = 4 waves, wave w owns (mh=w&1, nh=w>>1) 16x16 tile.
// fp32 adj -> bf16 in LDS (pad +8 -> 2-way bank aliasing, free). Register
// double-buffered global loads overlap HBM latency with MFMA phase.
// grid (256, 3) x 256  -> exactly 3 blocks/CU, balanced.
// ---------------------------------------------------------------------------
__global__ __launch_bounds__(256) void k_gemm(
    const float* __restrict__ adj_uu, const float* __restrict__ adj_cc,
    const float* __restrict__ adj_uc,
    const unsigned short* __restrict__ bt_uu, const unsigned short* __restrict__ bt_cc,
    const unsigned short* __restrict__ bt_uc,
    const float* __restrict__ dinv_uu, const float* __restrict__ dinv_cc,
    const float* __restrict__ du,
    float* __restrict__ out_u, float* __restrict__ c1, float* __restrict__ c2) {
  int m = blockIdx.y;
  const float* adj = (m == 0) ? adj_uu : (m == 1) ? adj_cc : adj_uc;
  const unsigned short* bt = (m == 0) ? bt_uu : (m == 1) ? bt_cc : bt_uc;
  const float* dsc = (m == 0) ? dinv_uu : (m == 1) ? dinv_cc : du;
  float* outp = (m == 0) ? out_u : (m == 1) ? c1 : c2;

  __shared__ unsigned short As[32][136];  // 272B row stride = 17x16B: aligned, 2-way bank alias
  __shared__ unsigned short Bs[32][136];

  int t = threadIdx.x;
  int w = t >> 6, l = t & 63;
  int mh = w & 1, nh = w >> 1;
  long r0 = (long)blockIdx.x * 32;

  int ar = t >> 3, ac = (t & 7) * 4;  // A staging: row, float-col base (4 float4 per thread)
  int bn = t >> 3, bk = (t & 7) * 8;  // B staging: n-row, k base (2 x ushort8 per thread)

  const float* ap = adj + (r0 + ar) * N_NODES + ac;
  const unsigned short* bp = bt + (long)bn * N_NODES + bk;

  float4 a0 = *(const float4*)(ap + 0);
  float4 a1 = *(const float4*)(ap + 32);
  float4 a2 = *(const float4*)(ap + 64);
  float4 a3 = *(const float4*)(ap + 96);
  ushort8 b0 = *(const ushort8*)(bp + 0);
  ushort8 b1 = *(const ushort8*)(bp + 64);

  floatx4 acc = {0.f, 0.f, 0.f, 0.f};

  for (int step = 0; step < 64; ++step) {
    ushort4v q;
    q.x = f2bf(a0.x); q.y = f2bf(a0.y); q.z = f2bf(a0.z); q.w = f2bf(a0.w);
    *(ushort4v*)&As[ar][ac + 0] = q;
    q.x = f2bf(a1.x); q.y = f2bf(a1.y); q.z = f2bf(a1.z); q.w = f2bf(a1.w);
    *(ushort4v*)&As[ar][ac + 32] = q;
    q.x = f2bf(a2.x); q.y = f2bf(a2.y); q.z = f2bf(a2.z); q.w = f2bf(a2.w);
    *(ushort4v*)&As[ar][ac + 64] = q;
    q.x = f2bf(a3.x); q.y = f2bf(a3.y); q.z = f2bf(a3.z); q.w = f2bf(a3.w);
    *(ushort4v*)&As[ar][ac + 96] = q;
    *(ushort8*)&Bs[bn][bk + 0] = b0;
    *(ushort8*)&Bs[bn][bk + 64] = b1;
    __syncthreads();

    if (step < 63) {  // prefetch next tile while MFMA phase runs
      ap += 128; bp += 128;
      a0 = *(const float4*)(ap + 0);
      a1 = *(const float4*)(ap + 32);
      a2 = *(const float4*)(ap + 64);
      a3 = *(const float4*)(ap + 96);
      b0 = *(const ushort8*)(bp + 0);
      b1 = *(const ushort8*)(bp + 64);
    }

#pragma unroll
    for (int kk = 0; kk < 4; ++kk) {
      short8 af = *(const short8*)&As[16 * mh + (l & 15)][kk * 32 + (l >> 4) * 8];
      short8 bf = *(const short8*)&Bs[16 * nh + (l & 15)][kk * 32 + (l >> 4) * 8];
      acc = __builtin_amdgcn_mfma_f32_16x16x32_bf16(af, bf, acc, 0, 0, 0);
    }
    __syncthreads();
  }

  // C/D layout (verified m89): col = lane&15, row = (lane>>4)*4 + reg
  int mrow = (int)r0 + 16 * mh + ((l >> 4) << 2);
  int ncol = 16 * nh + (l & 15);
#pragma unroll
  for (int r = 0; r < 4; ++r) {
    float sc = dsc[mrow + r];
    outp[(long)(mrow + r) * 32 + ncol] = sc * acc[r];
  }
}

// ---------------------------------------------------------------------------
// K_epi: attention + combine. 8 rows x 32 lanes per block. grid 1024 x 256
// out sections: [1]=node_embed_c, [2]=Y_c, [3]=Y_u
// ---------------------------------------------------------------------------
__global__ __launch_bounds__(256) void k_epilogue(
    const float* __restrict__ c1, const float* __restrict__ c2,
    const float* __restrict__ X_C, const float* __restrict__ W_lin,
    const float* __restrict__ a_vec, float* __restrict__ out) {
  __shared__ float Wl[64][32];
  __shared__ float al[32];
  int t = threadIdx.x;
#pragma unroll
  for (int i = 0; i < 8; ++i) {
    int idx = t + 256 * i;
    Wl[idx >> 5][idx & 31] = W_lin[idx];
  }
  if (t < 32) al[t] = a_vec[t];
  int g = t >> 5, n = t & 31;
  long row = (long)blockIdx.x * 8 + g;
  __syncthreads();
  float h1 = c1[row * 32 + n];
  float h2 = c2[row * 32 + n];
  float xv = X_C[row * 32 + n];
  float s1 = 0.f, s2 = 0.f, sx = 0.f;
#pragma unroll
  for (int k = 0; k < 32; ++k) {
    float h1k = __shfl(h1, k, 32);
    float h2k = __shfl(h2, k, 32);
    float xk = __shfl(xv, k, 32);
    float w0 = Wl[k][n], w1 = Wl[32 + k][n];
    s1 += h1k * w0;
    s2 += h2k * w0;
    sx += xk * w1;
  }
  float t1 = fmaxf(s1 + sx, 0.f) * al[n];
  float t2 = fmaxf(s2 + sx, 0.f) * al[n];
#pragma unroll
  for (int off = 16; off >= 1; off >>= 1) {
    t1 += __shfl_xor(t1, off, 32);
    t2 += __shfl_xor(t2, off, 32);
  }
  float mx = fmaxf(t1, t2);
  float e1 = expf(t1 - mx), e2 = expf(t2 - mx);
  float inv = 1.0f / (e1 + e2);
  float w1w = e1 * inv, w2w = e2 * inv;
  float yc = w1w * h1, yu = w2w * h2;
  long o = row * 32 + n;
  out[262144 + o] = yc + yu;  // node_embed_c
  out[524288 + o] = yc;       // Y_c
  out[786432 + o] = yu;       // Y_u
}

extern "C" void kernel_launch(void* const* d_in, const int* in_sizes, int n_in,
                              void* d_out, int out_size, void* d_ws, size_t ws_size,
                              hipStream_t stream) {
  (void)in_sizes; (void)n_in; (void)out_size; (void)ws_size;
  const float* X_U = (const float*)d_in[0];
  const float* X_C = (const float*)d_in[1];
  const float* adj_uu = (const float*)d_in[2];
  const float* adj_uc = (const float*)d_in[3];
  const float* adj_cc = (const float*)d_in[4];
  const float* weight_s = (const float*)d_in[5];
  const float* proj_u = (const float*)d_in[6];
  // d_in[7] = proj_c, unused in forward math
  const float* weight_c = (const float*)d_in[8];
  const float* W_lin = (const float*)d_in[9];
  const float* a_vec = (const float*)d_in[10];
  float* out = (float*)d_out;

  char* ws = (char*)d_ws;
  auto alloc = [&](size_t bytes) {
    char* p = ws;
    ws += (bytes + 255) & ~(size_t)255;
    return p;
  };
  float* dinv_uu = (float*)alloc(8192 * 4);
  float* dinv_cc = (float*)alloc(8192 * 4);
  float* du = (float*)alloc(8192 * 4);
  float* dc = (float*)alloc(8192 * 4);
  float* rs_part = (float*)alloc((size_t)8 * 8192 * 4);
  float* cs_part = (float*)alloc((size_t)64 * 8192 * 4);
  float* P = (float*)alloc(1024 * 4);
  float* c1 = (float*)alloc((size_t)262144 * 4);
  float* c2 = (float*)alloc((size_t)262144 * 4);
  unsigned short* bt_uu = (unsigned short*)alloc((size_t)262144 * 2);
  unsigned short* bt_cc = (unsigned short*)alloc((size_t)262144 * 2);
  unsigned short* bt_uc = (unsigned short*)alloc((size_t)262144 * 2);

  hipLaunchKernelGGL(k_rowsum, dim3(2048, 2), dim3(256), 0, stream,
                     adj_uu, adj_cc, dinv_uu, dinv_cc);
  hipLaunchKernelGGL(k_uc_partials, dim3(64, 8), dim3(256), 0, stream,
                     adj_uc, rs_part, cs_part);
  hipLaunchKernelGGL(k_finalize, dim3(32), dim3(256), 0, stream,
                     rs_part, cs_part, du, dc);
  hipLaunchKernelGGL(k_projw, dim3(1), dim3(1024), 0, stream, proj_u, weight_c, P);
  hipLaunchKernelGGL(k_support, dim3(1024, 3), dim3(256), 0, stream,
                     X_U, X_C, weight_s, P, dinv_uu, dinv_cc, dc, bt_uu, bt_cc, bt_uc);
  hipLaunchKernelGGL(k_gemm, dim3(256, 3), dim3(256), 0, stream,
                     adj_uu, adj_cc, adj_uc, bt_uu, bt_cc, bt_uc,
                     dinv_uu, dinv_cc, du, out, c1, c2);
  hipLaunchKernelGGL(k_epilogue, dim3(1024), dim3(256), 0, stream,
                     c1, c2, X_C, W_lin, a_vec, out);
}